// Round 13
// baseline (191.733 us; speedup 1.0000x reference)
//
#include <hip/hip_runtime.h>
#include <math.h>

#define NNODES 100000
#define NEDGES 100000
#define NNZV   1600000
#define KDIM   64
#define LAMBDA 0.1f

#define NB    782        // ceil(100000/128) buckets (edge>>7 / node>>7)
#define BSH   7
#define BMASK 127
#define CAP   3072       // per-bucket capacity (mean 2048, sd~45)
#define A0B   256        // chunks (CHUNK elements each)
#define A0T   1024
#define CHUNK 6250       // NNZV / A0B exactly
#define YQB   1024       // blocks for yq kernel
#define GMB   512        // blocks for gmat kernel

// ---- workspace layout (bytes), all offsets 256-aligned ----
#define OFF_DV      0           // N f32 (fully written by dvb)
#define OFF_G       400128      // 4096 f32 (fully written by greduce)
#define OFF_PART    416512      // NB f32
#define OFF_ZN      419840      // YQB f32
#define OFF_GC1     423936      // NB u32 bucket cursors S1 (init + sort)
#define OFF_GC2     427264      // NB u32 bucket cursors S2
#define OFF_S1      430592      // NB*CAP u32 (edge-bucketed: node|elocal<<17)
#define OFF_S2      10039808    // NB*CAP u32 (node-bucketed: edge|nlocal<<17)
#define OFF_YQ      19649024    // N*K fp8 = 6400000 (16B-aligned rows)
#define OFF_GPART   26049024    // GMB*4096 f32 = 8388608
// total 34437632

#if defined(__has_builtin)
#if __has_builtin(__builtin_amdgcn_cvt_f32_fp8)
#define HAS_CVT_FP8 1
#endif
#if __has_builtin(__builtin_amdgcn_cvt_pk_fp8_f32)
#define HAS_PK_FP8 1
#endif
#endif

__device__ __forceinline__ int load_node(const unsigned* idx, int i, bool i64) {
    return (int)(i64 ? idx[2 * i] : idx[i]);
}
__device__ __forceinline__ int load_edge(const unsigned* idx, int i, bool i64) {
    return (int)(i64 ? idx[2 * (NNZV + i)] : idx[NNZV + i]);
}

// f32 -> fp8 e4m3fn, RNE (fallback when no HW packed cvt).
__device__ __forceinline__ unsigned char enc_fp8(float x) {
    unsigned u = __float_as_uint(x);
    unsigned s = (u >> 31) << 7;
    unsigned mag = u & 0x7FFFFFFFu;
    if (mag >= 0x43E00000u) return (unsigned char)(s | 0x7Eu);
    if (mag < 0x3C800000u) {
        float a = __uint_as_float(mag);
        int m = (int)rintf(a * 512.0f);
        if (m >= 8) return (unsigned char)(s | 0x08u);
        return (unsigned char)(s | (unsigned)m);
    }
    unsigned lsb = (mag >> 20) & 1u;
    mag += 0x0007FFFFu + lsb;
    unsigned e = (mag >> 23) - 120u;
    return (unsigned char)(s | (e << 3) | ((mag >> 20) & 7u));
}

// Pack 4 f32 -> 4 fp8 bytes (HW packed converter when available).
__device__ __forceinline__ unsigned pack_fp8x4(float y0, float y1, float y2, float y3) {
#ifdef HAS_PK_FP8
    int q = 0;
    q = __builtin_amdgcn_cvt_pk_fp8_f32(y0, y1, q, false);
    q = __builtin_amdgcn_cvt_pk_fp8_f32(y2, y3, q, true);
    return (unsigned)q;
#else
    return (unsigned)enc_fp8(y0) | ((unsigned)enc_fp8(y1) << 8) |
           ((unsigned)enc_fp8(y2) << 16) | ((unsigned)enc_fp8(y3) << 24);
#endif
}

// fp8 e4m3fn byte SEL of v -> f32.
template <int SEL>
__device__ __forceinline__ float dec_fp8(unsigned v) {
#ifdef HAS_CVT_FP8
    return __builtin_amdgcn_cvt_f32_fp8(v, SEL);
#else
    unsigned b = (v >> (8 * SEL)) & 0xFFu;
    unsigned e = (b >> 3) & 15u, m = b & 7u;
    float f = e ? __uint_as_float(((e + 120u) << 23) | (m << 20))
                : (float)m * 0.001953125f;
    return (b & 128u) ? -f : f;
#endif
}

// Seed bucket cursors to their bucket base.
__global__ void init_kernel(unsigned* __restrict__ gcur1, unsigned* __restrict__ gcur2) {
    int b = blockIdx.x * 256 + threadIdx.x;
    if (b < NB) {
        gcur1[b] = (unsigned)b * CAP;
        gcur2[b] = (unsigned)b * CAP;
    }
}

// Fused histogram + scan + LDS-staged scatter with GLOBAL atomic range
// reservation. Grid 2*A0B: which selects S1/S2.
__global__ __launch_bounds__(A0T) void sort_kernel(const unsigned* __restrict__ idx,
                                                   unsigned* __restrict__ gcur1,
                                                   unsigned* __restrict__ gcur2,
                                                   unsigned* __restrict__ S1,
                                                   unsigned* __restrict__ S2) {
    __shared__ unsigned stage[CHUNK];
    __shared__ unsigned lhist[NB], lcur[NB], gbase[NB];
    __shared__ unsigned wsum[16], fred[16];
    int which = blockIdx.x >> 8, chunk = blockIdx.x & (A0B - 1);
    int t = threadIdx.x, wave = t >> 6, lane = t & 63;

    unsigned hv = idx[2 * t + 1];
#pragma unroll
    for (int off = 32; off; off >>= 1) hv |= __shfl_xor(hv, off);
    if (lane == 0) fred[wave] = hv;
    for (int j = t; j < NB; j += A0T) lhist[j] = 0u;
    __syncthreads();
    unsigned o = 0;
#pragma unroll
    for (int k = 0; k < 16; ++k) o |= fred[k];
    bool i64 = (o == 0u);

    int base = chunk * CHUNK;
    if (which == 0) {
        for (int i = base + t; i < base + CHUNK; i += A0T)
            atomicAdd(&lhist[load_edge(idx, i, i64) >> BSH], 1u);
    } else {
        for (int i = base + t; i < base + CHUNK; i += A0T)
            atomicAdd(&lhist[load_node(idx, i, i64) >> BSH], 1u);
    }
    __syncthreads();

    unsigned v = (t < NB) ? lhist[t] : 0u;
    unsigned x = v;
#pragma unroll
    for (int off = 1; off < 64; off <<= 1) {
        unsigned y = __shfl_up(x, off);
        if (lane >= off) x += y;
    }
    if (lane == 63) wsum[wave] = x;
    __syncthreads();
    if (t < 16) {
        unsigned a = wsum[t], y = a;
#pragma unroll
        for (int off = 1; off < 16; off <<= 1) {
            unsigned z = __shfl_up(y, off);
            if (t >= off) y += z;
        }
        wsum[t] = y - a;
    }
    __syncthreads();
    if (t < NB) lcur[t] = wsum[wave] + x - v;
    __syncthreads();

    for (int i = base + t; i < base + CHUNK; i += A0T) {
        int node = load_node(idx, i, i64);
        int edge = load_edge(idx, i, i64);
        unsigned key, val;
        if (which == 0) {
            key = (unsigned)edge >> BSH;
            val = (unsigned)node | ((unsigned)(edge & BMASK) << 17);
        } else {
            key = (unsigned)node >> BSH;
            val = (unsigned)edge | ((unsigned)(node & BMASK) << 17);
        }
        unsigned p = atomicAdd(&lcur[key], 1u);
        stage[p] = val;
    }
    __syncthreads();

    unsigned* gcur = which ? gcur2 : gcur1;
    if (t < NB) {
        unsigned c = lhist[t];
        gbase[t] = c ? atomicAdd(&gcur[t], c) : 0u;
    }
    __syncthreads();

    unsigned* S = which ? S2 : S1;
    int li = lane & 7;
    for (int bb = wave * 8 + (lane >> 3); bb < NB; bb += 128) {
        unsigned c = lhist[bb];
        unsigned st = lcur[bb] - c;
        unsigned g = gbase[bb];
        for (unsigned m = li; m < c; m += 8) S[g + m] = stage[st + m];
    }
}

// Dv build: per node-bucket LDS f32 accumulation (w gathered from L2).
__global__ __launch_bounds__(256) void dvb_kernel(const unsigned* __restrict__ S2,
                                                  const unsigned* __restrict__ gcur2,
                                                  const float* __restrict__ w,
                                                  float* __restrict__ Dv) {
    __shared__ float acc[128];
    int t = threadIdx.x, b = blockIdx.x;
    if (t < 128) acc[t] = 0.0f;
    __syncthreads();
    unsigned cnt = gcur2[b] - (unsigned)b * CAP;
    const unsigned* src = S2 + (size_t)b * CAP;
    for (unsigned i = t; i < cnt; i += 256) {
        unsigned e = src[i];
        atomicAdd(&acc[e >> 17], w[e & 0x1FFFFu]);
    }
    __syncthreads();
    int node = b * 128 + t;
    if (t < 128 && node < NNODES) Dv[node] = acc[t];
}

// yq: Yq = fp8(Z * rsqrt(clamp(Dv))) + term1 partials. Barrier-free stream.
__global__ __launch_bounds__(256) void yq_kernel(const float* __restrict__ Z,
                                                 const float* __restrict__ Dv,
                                                 unsigned* __restrict__ Yq32,
                                                 float* __restrict__ ZN) {
    __shared__ float red[256];
    int t = threadIdx.x;
    float zn = 0.0f;
    for (int i4 = blockIdx.x * 256 + t; i4 < NNODES * 16; i4 += YQB * 256) {
        float4 v = ((const float4*)Z)[i4];
        float d = Dv[i4 >> 4];
        bool good = d > 0.0f;
        float r = good ? rsqrtf(d) : 1.0f;
        zn += good ? (v.x * v.x + v.y * v.y + v.z * v.z + v.w * v.w) : 0.0f;
        Yq32[i4] = pack_fp8x4(v.x * r, v.y * r, v.z * r, v.w * r);
    }
    red[t] = zn;
    __syncthreads();
    for (int s = 128; s > 0; s >>= 1) {
        if (t < s) red[t] += red[t + s];
        __syncthreads();
    }
    if (t == 0) ZN[blockIdx.x] = red[0];
}

// gmat: partial G = Y^T Y from fp8 Yq (6.4 MB). 64-row LDS tiles.
__global__ __launch_bounds__(256) void gmat_kernel(const unsigned* __restrict__ Yq32,
                                                   float* __restrict__ Gpart) {
    __shared__ float ys[64][KDIM];
    float acc[16];
#pragma unroll
    for (int i = 0; i < 16; ++i) acc[i] = 0.0f;
    int t = threadIdx.x;
    int c = t & 63;
    int r0 = (t >> 6) * 16;
    for (int base = blockIdx.x * 64; base < NNODES; base += GMB * 64) {
        int rows = min(64, NNODES - base);
        __syncthreads();
        for (int j = t; j < rows * 16; j += 256) {
            unsigned v = Yq32[base * 16 + j];
            int row = j >> 4, q4 = (j & 15) * 4;
            ys[row][q4 + 0] = dec_fp8<0>(v);
            ys[row][q4 + 1] = dec_fp8<1>(v);
            ys[row][q4 + 2] = dec_fp8<2>(v);
            ys[row][q4 + 3] = dec_fp8<3>(v);
        }
        __syncthreads();
#pragma unroll 4
        for (int i = 0; i < rows; ++i) {
            float yc = ys[i][c];
#pragma unroll
            for (int rr = 0; rr < 16; ++rr) acc[rr] += ys[i][r0 + rr] * yc;
        }
    }
    float* gp = Gpart + (size_t)blockIdx.x * (KDIM * KDIM);
#pragma unroll
    for (int rr = 0; rr < 16; ++rr) gp[(r0 + rr) * KDIM + c] = acc[rr];
}

// Reduce Gpart[GMB][4096] -> G[4096]. 128 blocks x 256 threads.
__global__ __launch_bounds__(256) void greduce_kernel(const float* __restrict__ Gpart,
                                                      float* __restrict__ G) {
    __shared__ float r[256];
    int t = threadIdx.x;
    int e0 = blockIdx.x * 32;
    int psub = t >> 5, e = e0 + (t & 31);
    float s = 0.0f;
    for (int p = psub; p < GMB; p += 8)
        s += Gpart[(size_t)p * (KDIM * KDIM) + e];
    r[t] = s;
    __syncthreads();
    if (t < 32) {
        float v = r[t];
#pragma unroll
        for (int k = 1; k < 8; ++k) v += r[t + 32 * k];
        G[e0 + t] = v;
    }
}

// Per-bucket edge term. Register-staged entries -> LDS counting sort ->
// uint4 (16B) gather: lane = (member slot ms=lane>>2, quad q=lane&3); one
// load instruction covers 16 members. Butterfly-reduce over ms bits.
__global__ __launch_bounds__(512) void bedge_kernel(const uint4* __restrict__ Yq16,
                                                    const float* __restrict__ w,
                                                    const unsigned* __restrict__ S1,
                                                    const unsigned* __restrict__ gcur1,
                                                    float* __restrict__ part) {
    __shared__ unsigned lhist[128], loffs[128], lcur[128];
    __shared__ unsigned snode[CAP];
    __shared__ float wred[8];
    int t = threadIdx.x, b = blockIdx.x;
    if (t < 128) lhist[t] = 0u;
    __syncthreads();
    unsigned cnt = gcur1[b] - (unsigned)b * CAP;
    const unsigned* src = S1 + (size_t)b * CAP;
    // register-stage up to 6 entries per thread (CAP = 6*512)
    unsigned e0 = (t + 0 * 512 < cnt) ? src[t + 0 * 512] : ~0u;
    unsigned e1 = (t + 1 * 512 < cnt) ? src[t + 1 * 512] : ~0u;
    unsigned e2 = (t + 2 * 512 < cnt) ? src[t + 2 * 512] : ~0u;
    unsigned e3 = (t + 3 * 512 < cnt) ? src[t + 3 * 512] : ~0u;
    unsigned e4 = (t + 4 * 512 < cnt) ? src[t + 4 * 512] : ~0u;
    unsigned e5 = (t + 5 * 512 < cnt) ? src[t + 5 * 512] : ~0u;
    if (e0 != ~0u) atomicAdd(&lhist[e0 >> 17], 1u);
    if (e1 != ~0u) atomicAdd(&lhist[e1 >> 17], 1u);
    if (e2 != ~0u) atomicAdd(&lhist[e2 >> 17], 1u);
    if (e3 != ~0u) atomicAdd(&lhist[e3 >> 17], 1u);
    if (e4 != ~0u) atomicAdd(&lhist[e4 >> 17], 1u);
    if (e5 != ~0u) atomicAdd(&lhist[e5 >> 17], 1u);
    __syncthreads();
    if (t < 64) {
        unsigned a = lhist[2 * t], bb = lhist[2 * t + 1];
        unsigned sp = a + bb, x = sp;
#pragma unroll
        for (int off = 1; off < 64; off <<= 1) {
            unsigned y = __shfl_up(x, off);
            if (t >= off) x += y;
        }
        unsigned ex = x - sp;
        loffs[2 * t] = ex;          lcur[2 * t] = ex;
        loffs[2 * t + 1] = ex + a;  lcur[2 * t + 1] = ex + a;
    }
    __syncthreads();
    if (e0 != ~0u) snode[atomicAdd(&lcur[e0 >> 17], 1u)] = e0 & 0x1FFFFu;
    if (e1 != ~0u) snode[atomicAdd(&lcur[e1 >> 17], 1u)] = e1 & 0x1FFFFu;
    if (e2 != ~0u) snode[atomicAdd(&lcur[e2 >> 17], 1u)] = e2 & 0x1FFFFu;
    if (e3 != ~0u) snode[atomicAdd(&lcur[e3 >> 17], 1u)] = e3 & 0x1FFFFu;
    if (e4 != ~0u) snode[atomicAdd(&lcur[e4 >> 17], 1u)] = e4 & 0x1FFFFu;
    if (e5 != ~0u) snode[atomicAdd(&lcur[e5 >> 17], 1u)] = e5 & 0x1FFFFu;
    __syncthreads();
    int wv = t >> 6, lane = t & 63, ms = lane >> 2, q = lane & 3;
    float acc = 0.0f;
    for (int el = wv; el < 128; el += 8) {
        unsigned n = lhist[el];
        if (!n) continue;
        unsigned beg = loffs[el];
        float s[16];
#pragma unroll
        for (int k = 0; k < 16; ++k) s[k] = 0.0f;
        for (unsigned m = 0; m < n; m += 16) {
            unsigned mi = m + (unsigned)ms;
            bool ok = mi < n;
            unsigned nd = snode[beg + (ok ? mi : 0)];
            uint4 v = Yq16[nd * 4u + (unsigned)q];
            if (ok) {
                s[0] += dec_fp8<0>(v.x); s[1] += dec_fp8<1>(v.x);
                s[2] += dec_fp8<2>(v.x); s[3] += dec_fp8<3>(v.x);
                s[4] += dec_fp8<0>(v.y); s[5] += dec_fp8<1>(v.y);
                s[6] += dec_fp8<2>(v.y); s[7] += dec_fp8<3>(v.y);
                s[8] += dec_fp8<0>(v.z); s[9] += dec_fp8<1>(v.z);
                s[10] += dec_fp8<2>(v.z); s[11] += dec_fp8<3>(v.z);
                s[12] += dec_fp8<0>(v.w); s[13] += dec_fp8<1>(v.w);
                s[14] += dec_fp8<2>(v.w); s[15] += dec_fp8<3>(v.w);
            }
        }
        // combine 16 member slots (lane bits 2..5)
#pragma unroll
        for (int off = 4; off <= 32; off <<= 1) {
#pragma unroll
            for (int k = 0; k < 16; ++k) s[k] += __shfl_xor(s[k], off);
        }
        float aa = 0.0f;
#pragma unroll
        for (int k = 0; k < 16; ++k) aa += s[k] * s[k];
        aa += __shfl_xor(aa, 1); aa += __shfl_xor(aa, 2);
        if (lane == 0) acc += (w[b * 128 + el] / (float)n) * aa;
    }
    if (lane == 0) wred[wv] = acc;
    __syncthreads();
    if (t == 0) {
        float s = 0.0f;
        for (int i = 0; i < 8; ++i) s += wred[i];
        part[b] = s;
    }
}

// Final: out = sum(ZN) - sum(part) + LAMBDA * ||G - I||_F
__global__ void final_kernel(const float* __restrict__ G,
                             const float* __restrict__ ZN,
                             const float* __restrict__ part,
                             float* __restrict__ out) {
    __shared__ float r1[256], r2[256];
    int t = threadIdx.x;
    float zn = 0.0f, pe = 0.0f, gg = 0.0f;
    for (int i = t; i < YQB; i += 256) zn += ZN[i];
    for (int i = t; i < NB; i += 256) pe += part[i];
    for (int i = t; i < KDIM * KDIM; i += 256) {
        int r = i >> 6, c = i & 63;
        float g = G[i] - ((r == c) ? 1.0f : 0.0f);
        gg += g * g;
    }
    r1[t] = zn - pe; r2[t] = gg;
    __syncthreads();
    for (int s = 128; s > 0; s >>= 1) {
        if (t < s) { r1[t] += r1[t + s]; r2[t] += r2[t + s]; }
        __syncthreads();
    }
    if (t == 0) out[0] = r1[0] + LAMBDA * sqrtf(r2[0]);
}

extern "C" void kernel_launch(void* const* d_in, const int* in_sizes, int n_in,
                              void* d_out, int out_size, void* d_ws, size_t ws_size,
                              hipStream_t stream) {
    const float* Z = (const float*)d_in[0];
    const unsigned* idx = (const unsigned*)d_in[1];
    const float* w = (const float*)d_in[3];
    float* out = (float*)d_out;
    char* ws = (char*)d_ws;

    float* Dv       = (float*)(ws + OFF_DV);
    float* G        = (float*)(ws + OFF_G);
    float* part     = (float*)(ws + OFF_PART);
    float* ZN       = (float*)(ws + OFF_ZN);
    unsigned* gcur1 = (unsigned*)(ws + OFF_GC1);
    unsigned* gcur2 = (unsigned*)(ws + OFF_GC2);
    unsigned* S1    = (unsigned*)(ws + OFF_S1);
    unsigned* S2    = (unsigned*)(ws + OFF_S2);
    unsigned* Yq32  = (unsigned*)(ws + OFF_YQ);
    float* Gpart    = (float*)(ws + OFF_GPART);

    init_kernel<<<4, 256, 0, stream>>>(gcur1, gcur2);
    sort_kernel<<<2 * A0B, A0T, 0, stream>>>(idx, gcur1, gcur2, S1, S2);
    dvb_kernel<<<NB, 256, 0, stream>>>(S2, gcur2, w, Dv);
    yq_kernel<<<YQB, 256, 0, stream>>>(Z, Dv, Yq32, ZN);
    bedge_kernel<<<NB, 512, 0, stream>>>((const uint4*)Yq32, w, S1, gcur1, part);
    gmat_kernel<<<GMB, 256, 0, stream>>>(Yq32, Gpart);
    greduce_kernel<<<128, 256, 0, stream>>>(Gpart, G);
    final_kernel<<<1, 256, 0, stream>>>(G, ZN, part, out);
}

// Round 14
// 118.166 us; speedup vs baseline: 1.6226x; 1.6226x over previous
//
#include <hip/hip_runtime.h>
#include <math.h>

#define NNODES 100000
#define NEDGES 100000
#define NNZV   1600000
#define KDIM   64
#define LAMBDA 0.1f

#define NB    782        // ceil(100000/128) buckets (edge>>7 / node>>7)
#define BSH   7
#define BMASK 127
#define CAP   3072       // per-bucket capacity (mean 2048, sd~45)
#define A0B   256        // chunks (CHUNK elements each)
#define A0T   1024
#define CHUNK 6250       // NNZV / A0B exactly
#define GMB   512        // blocks for gmat kernel

// ---- workspace layout (bytes), all offsets 256-aligned ----
#define OFF_G       0           // 4096 f32 (zeroed by init, atomic accum)
#define OFF_PART    16384       // NB f32
#define OFF_ZN      19712       // NB f32
#define OFF_GC1     23040       // NB u32 bucket cursors S1
#define OFF_GC2     26368       // NB u32 bucket cursors S2
#define OFF_S1      29696       // NB*CAP u32 (edge-bucketed: node|elocal<<17)
#define OFF_S2      9638912     // NB*CAP u32 (node-bucketed: edge|nlocal<<17)
#define OFF_YQ      19248128    // N*K fp8 = 6400000
// total 25648128

#if defined(__has_builtin)
#if __has_builtin(__builtin_amdgcn_cvt_f32_fp8)
#define HAS_CVT_FP8 1
#endif
#if __has_builtin(__builtin_amdgcn_cvt_pk_fp8_f32)
#define HAS_PK_FP8 1
#endif
#if __has_builtin(__builtin_amdgcn_cvt_pk_f32_fp8)
#define HAS_PK_F32_FP8 1
typedef float f32x2 __attribute__((ext_vector_type(2)));
#endif
#endif

__device__ __forceinline__ int load_node(const unsigned* idx, int i, bool i64) {
    return (int)(i64 ? idx[2 * i] : idx[i]);
}
__device__ __forceinline__ int load_edge(const unsigned* idx, int i, bool i64) {
    return (int)(i64 ? idx[2 * (NNZV + i)] : idx[NNZV + i]);
}

// f32 -> fp8 e4m3fn, RNE (fallback when no HW packed cvt).
__device__ __forceinline__ unsigned char enc_fp8(float x) {
    unsigned u = __float_as_uint(x);
    unsigned s = (u >> 31) << 7;
    unsigned mag = u & 0x7FFFFFFFu;
    if (mag >= 0x43E00000u) return (unsigned char)(s | 0x7Eu);
    if (mag < 0x3C800000u) {
        float a = __uint_as_float(mag);
        int m = (int)rintf(a * 512.0f);
        if (m >= 8) return (unsigned char)(s | 0x08u);
        return (unsigned char)(s | (unsigned)m);
    }
    unsigned lsb = (mag >> 20) & 1u;
    mag += 0x0007FFFFu + lsb;
    unsigned e = (mag >> 23) - 120u;
    return (unsigned char)(s | (e << 3) | ((mag >> 20) & 7u));
}

// Pack 4 f32 -> 4 fp8 bytes (HW packed converter when available).
__device__ __forceinline__ unsigned pack_fp8x4(float y0, float y1, float y2, float y3) {
#ifdef HAS_PK_FP8
    int q = 0;
    q = __builtin_amdgcn_cvt_pk_fp8_f32(y0, y1, q, false);
    q = __builtin_amdgcn_cvt_pk_fp8_f32(y2, y3, q, true);
    return (unsigned)q;
#else
    return (unsigned)enc_fp8(y0) | ((unsigned)enc_fp8(y1) << 8) |
           ((unsigned)enc_fp8(y2) << 16) | ((unsigned)enc_fp8(y3) << 24);
#endif
}

// fp8 e4m3fn byte SEL of v -> f32 (scalar path).
template <int SEL>
__device__ __forceinline__ float dec_fp8(unsigned v) {
#ifdef HAS_CVT_FP8
    return __builtin_amdgcn_cvt_f32_fp8(v, SEL);
#else
    unsigned b = (v >> (8 * SEL)) & 0xFFu;
    unsigned e = (b >> 3) & 15u, m = b & 7u;
    float f = e ? __uint_as_float(((e + 120u) << 23) | (m << 20))
                : (float)m * 0.001953125f;
    return (b & 128u) ? -f : f;
#endif
}

// Decode all 4 fp8 bytes of v (packed HW cvt when available: 2 instructions).
__device__ __forceinline__ void dec4_fp8(unsigned v, float& a0, float& a1,
                                         float& a2, float& a3) {
#ifdef HAS_PK_F32_FP8
    f32x2 lo = __builtin_amdgcn_cvt_pk_f32_fp8((int)v, false);
    f32x2 hi = __builtin_amdgcn_cvt_pk_f32_fp8((int)v, true);
    a0 = lo.x; a1 = lo.y; a2 = hi.x; a3 = hi.y;
#else
    a0 = dec_fp8<0>(v); a1 = dec_fp8<1>(v);
    a2 = dec_fp8<2>(v); a3 = dec_fp8<3>(v);
#endif
}

// Seed bucket cursors and zero G (replaces hipMemsetAsync fill kernel).
__global__ void init_kernel(unsigned* __restrict__ gcur1,
                            unsigned* __restrict__ gcur2,
                            float* __restrict__ G) {
    int i = blockIdx.x * 256 + threadIdx.x;
    if (i < NB) {
        gcur1[i] = (unsigned)i * CAP;
        gcur2[i] = (unsigned)i * CAP;
    }
    if (i < KDIM * KDIM) G[i] = 0.0f;
}

// Fused histogram + scan + LDS-staged scatter with GLOBAL atomic range
// reservation. Grid 2*A0B: which selects S1/S2.
__global__ __launch_bounds__(A0T) void sort_kernel(const unsigned* __restrict__ idx,
                                                   unsigned* __restrict__ gcur1,
                                                   unsigned* __restrict__ gcur2,
                                                   unsigned* __restrict__ S1,
                                                   unsigned* __restrict__ S2) {
    __shared__ unsigned stage[CHUNK];
    __shared__ unsigned lhist[NB], lcur[NB], gbase[NB];
    __shared__ unsigned wsum[16], fred[16];
    int which = blockIdx.x >> 8, chunk = blockIdx.x & (A0B - 1);
    int t = threadIdx.x, wave = t >> 6, lane = t & 63;

    unsigned hv = idx[2 * t + 1];
#pragma unroll
    for (int off = 32; off; off >>= 1) hv |= __shfl_xor(hv, off);
    if (lane == 0) fred[wave] = hv;
    for (int j = t; j < NB; j += A0T) lhist[j] = 0u;
    __syncthreads();
    unsigned o = 0;
#pragma unroll
    for (int k = 0; k < 16; ++k) o |= fred[k];
    bool i64 = (o == 0u);

    int base = chunk * CHUNK;
    if (which == 0) {
        for (int i = base + t; i < base + CHUNK; i += A0T)
            atomicAdd(&lhist[load_edge(idx, i, i64) >> BSH], 1u);
    } else {
        for (int i = base + t; i < base + CHUNK; i += A0T)
            atomicAdd(&lhist[load_node(idx, i, i64) >> BSH], 1u);
    }
    __syncthreads();

    unsigned v = (t < NB) ? lhist[t] : 0u;
    unsigned x = v;
#pragma unroll
    for (int off = 1; off < 64; off <<= 1) {
        unsigned y = __shfl_up(x, off);
        if (lane >= off) x += y;
    }
    if (lane == 63) wsum[wave] = x;
    __syncthreads();
    if (t < 16) {
        unsigned a = wsum[t], y = a;
#pragma unroll
        for (int off = 1; off < 16; off <<= 1) {
            unsigned z = __shfl_up(y, off);
            if (t >= off) y += z;
        }
        wsum[t] = y - a;
    }
    __syncthreads();
    if (t < NB) lcur[t] = wsum[wave] + x - v;
    __syncthreads();

    for (int i = base + t; i < base + CHUNK; i += A0T) {
        int node = load_node(idx, i, i64);
        int edge = load_edge(idx, i, i64);
        unsigned key, val;
        if (which == 0) {
            key = (unsigned)edge >> BSH;
            val = (unsigned)node | ((unsigned)(edge & BMASK) << 17);
        } else {
            key = (unsigned)node >> BSH;
            val = (unsigned)edge | ((unsigned)(node & BMASK) << 17);
        }
        unsigned p = atomicAdd(&lcur[key], 1u);
        stage[p] = val;
    }
    __syncthreads();

    unsigned* gcur = which ? gcur2 : gcur1;
    if (t < NB) {
        unsigned c = lhist[t];
        gbase[t] = c ? atomicAdd(&gcur[t], c) : 0u;
    }
    __syncthreads();

    unsigned* S = which ? S2 : S1;
    int li = lane & 7;
    for (int bb = wave * 8 + (lane >> 3); bb < NB; bb += 128) {
        unsigned c = lhist[bb];
        unsigned st = lcur[bb] - c;
        unsigned g = gbase[bb];
        for (unsigned m = li; m < c; m += 8) S[g + m] = stage[st + m];
    }
}

// Fused Dv + Yq + term1: block b accumulates Dv for its 128 nodes in LDS,
// then normalizes/encodes those 128 Z-rows to fp8 and reduces term1.
__global__ __launch_bounds__(256) void dvyq_kernel(const unsigned* __restrict__ S2,
                                                   const unsigned* __restrict__ gcur2,
                                                   const float* __restrict__ w,
                                                   const float* __restrict__ Z,
                                                   unsigned* __restrict__ Yq32,
                                                   float* __restrict__ ZN) {
    __shared__ float accd[128];
    __shared__ float red[256];
    int t = threadIdx.x, b = blockIdx.x;
    if (t < 128) accd[t] = 0.0f;
    __syncthreads();
    unsigned cnt = gcur2[b] - (unsigned)b * CAP;
    const unsigned* src = S2 + (size_t)b * CAP;
    for (unsigned i = t; i < cnt; i += 256) {
        unsigned e = src[i];
        atomicAdd(&accd[e >> 17], w[e & 0x1FFFFu]);
    }
    __syncthreads();
    int base = b * 128;
    float zn = 0.0f;
    for (int j = t; j < 128 * 16; j += 256) {
        int row = j >> 4, q = j & 15;
        int node = base + row;
        if (node < NNODES) {
            float4 v = ((const float4*)Z)[node * 16 + q];
            float d = accd[row];
            bool good = d > 0.0f;
            float r = good ? rsqrtf(d) : 1.0f;
            zn += good ? (v.x * v.x + v.y * v.y + v.z * v.z + v.w * v.w) : 0.0f;
            Yq32[node * 16 + q] = pack_fp8x4(v.x * r, v.y * r, v.z * r, v.w * r);
        }
    }
    red[t] = zn;
    __syncthreads();
    for (int s = 128; s > 0; s >>= 1) {
        if (t < s) red[t] += red[t + s];
        __syncthreads();
    }
    if (t == 0) ZN[b] = red[0];
}

// gmat: G += Y^T Y from fp8 Yq (6.4 MB). 64-row LDS tiles; atomic G merge
// (4096 addresses, 512 blocks -> benign; G zeroed by init_kernel).
__global__ __launch_bounds__(256) void gmat_kernel(const unsigned* __restrict__ Yq32,
                                                   float* __restrict__ G) {
    __shared__ float ys[64][KDIM];
    float acc[16];
#pragma unroll
    for (int i = 0; i < 16; ++i) acc[i] = 0.0f;
    int t = threadIdx.x;
    int c = t & 63;
    int r0 = (t >> 6) * 16;
    for (int base = blockIdx.x * 64; base < NNODES; base += GMB * 64) {
        int rows = min(64, NNODES - base);
        __syncthreads();
        for (int j = t; j < rows * 16; j += 256) {
            unsigned v = Yq32[base * 16 + j];
            int row = j >> 4, q4 = (j & 15) * 4;
            float x0, x1, x2, x3;
            dec4_fp8(v, x0, x1, x2, x3);
            ys[row][q4 + 0] = x0;
            ys[row][q4 + 1] = x1;
            ys[row][q4 + 2] = x2;
            ys[row][q4 + 3] = x3;
        }
        __syncthreads();
#pragma unroll 4
        for (int i = 0; i < rows; ++i) {
            float yc = ys[i][c];
#pragma unroll
            for (int rr = 0; rr < 16; ++rr) acc[rr] += ys[i][r0 + rr] * yc;
        }
    }
#pragma unroll
    for (int rr = 0; rr < 16; ++rr) atomicAdd(&G[(r0 + rr) * KDIM + c], acc[rr]);
}

// Per-bucket edge term (R12-proven structure): LDS counting sort over 128
// local edges, then fp8 gather with 2-edge interleave (8 loads in flight).
__global__ __launch_bounds__(512) void bedge_kernel(const unsigned* __restrict__ Yq32,
                                                    const float* __restrict__ w,
                                                    const unsigned* __restrict__ S1,
                                                    const unsigned* __restrict__ gcur1,
                                                    float* __restrict__ part) {
    __shared__ unsigned lhist[128], loffs[128], lcur[128];
    __shared__ unsigned snode[CAP];
    __shared__ float wred[8];
    int t = threadIdx.x, b = blockIdx.x;
    if (t < 128) lhist[t] = 0u;
    __syncthreads();
    unsigned cnt = gcur1[b] - (unsigned)b * CAP;
    const unsigned* src = S1 + (size_t)b * CAP;
    for (unsigned i = t; i < cnt; i += 512)
        atomicAdd(&lhist[src[i] >> 17], 1u);
    __syncthreads();
    if (t < 64) {
        unsigned a = lhist[2 * t], bb = lhist[2 * t + 1];
        unsigned sp = a + bb, x = sp;
#pragma unroll
        for (int off = 1; off < 64; off <<= 1) {
            unsigned y = __shfl_up(x, off);
            if (t >= off) x += y;
        }
        unsigned ex = x - sp;
        loffs[2 * t] = ex;          lcur[2 * t] = ex;
        loffs[2 * t + 1] = ex + a;  lcur[2 * t + 1] = ex + a;
    }
    __syncthreads();
    for (unsigned i = t; i < cnt; i += 512) {
        unsigned e = src[i];
        unsigned pos = atomicAdd(&lcur[e >> 17], 1u);
        snode[pos] = e & 0x1FFFFu;
    }
    __syncthreads();
    int wv = t >> 6, lane = t & 63, ms = lane >> 4, kq = lane & 15;
    float acc = 0.0f;
    for (int el = wv; el < 64; el += 8) {
        int eA = el, eB = el + 64;
        unsigned nA = lhist[eA], nB = lhist[eB];
        if (nA == 0 && nB == 0) continue;
        unsigned begA = loffs[eA], begB = loffs[eB];
        float a0 = 0, a1 = 0, a2 = 0, a3 = 0;
        float c0 = 0, c1 = 0, c2 = 0, c3 = 0;
        unsigned mmax = nA > nB ? nA : nB;
        for (unsigned m = 0; m < mmax; m += 16) {
            unsigned mA0 = m + (unsigned)ms, mA1 = mA0 + 4, mA2 = mA0 + 8, mA3 = mA0 + 12;
            bool oA0 = mA0 < nA, oA1 = mA1 < nA, oA2 = mA2 < nA, oA3 = mA3 < nA;
            bool oB0 = mA0 < nB, oB1 = mA1 < nB, oB2 = mA2 < nB, oB3 = mA3 < nB;
            unsigned nA0 = snode[oA0 ? begA + mA0 : 0];
            unsigned nA1 = snode[oA1 ? begA + mA1 : 0];
            unsigned nA2 = snode[oA2 ? begA + mA2 : 0];
            unsigned nA3 = snode[oA3 ? begA + mA3 : 0];
            unsigned nB0 = snode[oB0 ? begB + mA0 : 0];
            unsigned nB1 = snode[oB1 ? begB + mA1 : 0];
            unsigned nB2 = snode[oB2 ? begB + mA2 : 0];
            unsigned nB3 = snode[oB3 ? begB + mA3 : 0];
            // 8 independent gathers issued back-to-back (MLP)
            unsigned vA0 = Yq32[nA0 * 16u + (unsigned)kq];
            unsigned vA1 = Yq32[nA1 * 16u + (unsigned)kq];
            unsigned vA2 = Yq32[nA2 * 16u + (unsigned)kq];
            unsigned vA3 = Yq32[nA3 * 16u + (unsigned)kq];
            unsigned vB0 = Yq32[nB0 * 16u + (unsigned)kq];
            unsigned vB1 = Yq32[nB1 * 16u + (unsigned)kq];
            unsigned vB2 = Yq32[nB2 * 16u + (unsigned)kq];
            unsigned vB3 = Yq32[nB3 * 16u + (unsigned)kq];
            float x0, x1, x2, x3;
            dec4_fp8(vA0, x0, x1, x2, x3);
            if (oA0) { a0 += x0; a1 += x1; a2 += x2; a3 += x3; }
            dec4_fp8(vA1, x0, x1, x2, x3);
            if (oA1) { a0 += x0; a1 += x1; a2 += x2; a3 += x3; }
            dec4_fp8(vA2, x0, x1, x2, x3);
            if (oA2) { a0 += x0; a1 += x1; a2 += x2; a3 += x3; }
            dec4_fp8(vA3, x0, x1, x2, x3);
            if (oA3) { a0 += x0; a1 += x1; a2 += x2; a3 += x3; }
            dec4_fp8(vB0, x0, x1, x2, x3);
            if (oB0) { c0 += x0; c1 += x1; c2 += x2; c3 += x3; }
            dec4_fp8(vB1, x0, x1, x2, x3);
            if (oB1) { c0 += x0; c1 += x1; c2 += x2; c3 += x3; }
            dec4_fp8(vB2, x0, x1, x2, x3);
            if (oB2) { c0 += x0; c1 += x1; c2 += x2; c3 += x3; }
            dec4_fp8(vB3, x0, x1, x2, x3);
            if (oB3) { c0 += x0; c1 += x1; c2 += x2; c3 += x3; }
        }
        a0 += __shfl_xor(a0, 16); a0 += __shfl_xor(a0, 32);
        a1 += __shfl_xor(a1, 16); a1 += __shfl_xor(a1, 32);
        a2 += __shfl_xor(a2, 16); a2 += __shfl_xor(a2, 32);
        a3 += __shfl_xor(a3, 16); a3 += __shfl_xor(a3, 32);
        c0 += __shfl_xor(c0, 16); c0 += __shfl_xor(c0, 32);
        c1 += __shfl_xor(c1, 16); c1 += __shfl_xor(c1, 32);
        c2 += __shfl_xor(c2, 16); c2 += __shfl_xor(c2, 32);
        c3 += __shfl_xor(c3, 16); c3 += __shfl_xor(c3, 32);
        float aa = a0 * a0 + a1 * a1 + a2 * a2 + a3 * a3;
        float cc = c0 * c0 + c1 * c1 + c2 * c2 + c3 * c3;
        aa += __shfl_xor(aa, 1); aa += __shfl_xor(aa, 2);
        aa += __shfl_xor(aa, 4); aa += __shfl_xor(aa, 8);
        cc += __shfl_xor(cc, 1); cc += __shfl_xor(cc, 2);
        cc += __shfl_xor(cc, 4); cc += __shfl_xor(cc, 8);
        if (lane == 0) {
            if (nA) acc += (w[b * 128 + eA] / (float)nA) * aa;
            if (nB) acc += (w[b * 128 + eB] / (float)nB) * cc;
        }
    }
    if (lane == 0) wred[wv] = acc;
    __syncthreads();
    if (t == 0) {
        float s = 0.0f;
        for (int i = 0; i < 8; ++i) s += wred[i];
        part[b] = s;
    }
}

// Final: out = sum(ZN) - sum(part) + LAMBDA * ||G - I||_F
__global__ void final_kernel(const float* __restrict__ G,
                             const float* __restrict__ ZN,
                             const float* __restrict__ part,
                             float* __restrict__ out) {
    __shared__ float r1[256], r2[256];
    int t = threadIdx.x;
    float zn = 0.0f, pe = 0.0f, gg = 0.0f;
    for (int i = t; i < NB; i += 256) { zn += ZN[i]; pe += part[i]; }
    for (int i = t; i < KDIM * KDIM; i += 256) {
        int r = i >> 6, c = i & 63;
        float g = G[i] - ((r == c) ? 1.0f : 0.0f);
        gg += g * g;
    }
    r1[t] = zn - pe; r2[t] = gg;
    __syncthreads();
    for (int s = 128; s > 0; s >>= 1) {
        if (t < s) { r1[t] += r1[t + s]; r2[t] += r2[t + s]; }
        __syncthreads();
    }
    if (t == 0) out[0] = r1[0] + LAMBDA * sqrtf(r2[0]);
}

extern "C" void kernel_launch(void* const* d_in, const int* in_sizes, int n_in,
                              void* d_out, int out_size, void* d_ws, size_t ws_size,
                              hipStream_t stream) {
    const float* Z = (const float*)d_in[0];
    const unsigned* idx = (const unsigned*)d_in[1];
    const float* w = (const float*)d_in[3];
    float* out = (float*)d_out;
    char* ws = (char*)d_ws;

    float* G        = (float*)(ws + OFF_G);
    float* part     = (float*)(ws + OFF_PART);
    float* ZN       = (float*)(ws + OFF_ZN);
    unsigned* gcur1 = (unsigned*)(ws + OFF_GC1);
    unsigned* gcur2 = (unsigned*)(ws + OFF_GC2);
    unsigned* S1    = (unsigned*)(ws + OFF_S1);
    unsigned* S2    = (unsigned*)(ws + OFF_S2);
    unsigned* Yq32  = (unsigned*)(ws + OFF_YQ);

    init_kernel<<<16, 256, 0, stream>>>(gcur1, gcur2, G);
    sort_kernel<<<2 * A0B, A0T, 0, stream>>>(idx, gcur1, gcur2, S1, S2);
    dvyq_kernel<<<NB, 256, 0, stream>>>(S2, gcur2, w, Z, Yq32, ZN);
    bedge_kernel<<<NB, 512, 0, stream>>>(Yq32, w, S1, gcur1, part);
    gmat_kernel<<<GMB, 256, 0, stream>>>(Yq32, G);
    final_kernel<<<1, 256, 0, stream>>>(G, ZN, part, out);
}

// Round 15
// 107.447 us; speedup vs baseline: 1.7844x; 1.0998x over previous
//
#include <hip/hip_runtime.h>
#include <math.h>

#define NNODES 100000
#define NEDGES 100000
#define NNZV   1600000
#define KDIM   64
#define LAMBDA 0.1f

#define NB    782        // ceil(100000/128) buckets (edge>>7 / node>>7)
#define BSH   7
#define BMASK 127
#define CAP   3072       // per-bucket capacity (mean 2048, sd~45)
#define A0B   256        // chunks (CHUNK elements each)
#define A0T   1024
#define CHUNK 6250       // NNZV / A0B exactly
#define GMB   256        // gmat blocks inside fused kernel

// ---- workspace layout (bytes), all offsets 256-aligned ----
#define OFF_G       0           // 4096 f32 (zeroed by init, atomic accum)
#define OFF_PART    16384       // NB f32
#define OFF_ZN      19712       // NB f32
#define OFF_GC1     23040       // NB u32 bucket cursors S1
#define OFF_GC2     26368       // NB u32 bucket cursors S2
#define OFF_S1      29696       // NB*CAP u32 (edge-bucketed: node|elocal<<17)
#define OFF_S2      9638912     // NB*CAP u32 (node-bucketed: edge|nlocal<<17)
#define OFF_YQ      19248128    // N*K fp8 = 6400000
// total 25648128

#if defined(__has_builtin)
#if __has_builtin(__builtin_amdgcn_cvt_f32_fp8)
#define HAS_CVT_FP8 1
#endif
#if __has_builtin(__builtin_amdgcn_cvt_pk_fp8_f32)
#define HAS_PK_FP8 1
#endif
#if __has_builtin(__builtin_amdgcn_cvt_pk_f32_fp8)
#define HAS_PK_F32_FP8 1
typedef float f32x2 __attribute__((ext_vector_type(2)));
#endif
#endif

__device__ __forceinline__ int load_node(const unsigned* idx, int i, bool i64) {
    return (int)(i64 ? idx[2 * i] : idx[i]);
}
__device__ __forceinline__ int load_edge(const unsigned* idx, int i, bool i64) {
    return (int)(i64 ? idx[2 * (NNZV + i)] : idx[NNZV + i]);
}

// f32 -> fp8 e4m3fn, RNE (fallback when no HW packed cvt).
__device__ __forceinline__ unsigned char enc_fp8(float x) {
    unsigned u = __float_as_uint(x);
    unsigned s = (u >> 31) << 7;
    unsigned mag = u & 0x7FFFFFFFu;
    if (mag >= 0x43E00000u) return (unsigned char)(s | 0x7Eu);
    if (mag < 0x3C800000u) {
        float a = __uint_as_float(mag);
        int m = (int)rintf(a * 512.0f);
        if (m >= 8) return (unsigned char)(s | 0x08u);
        return (unsigned char)(s | (unsigned)m);
    }
    unsigned lsb = (mag >> 20) & 1u;
    mag += 0x0007FFFFu + lsb;
    unsigned e = (mag >> 23) - 120u;
    return (unsigned char)(s | (e << 3) | ((mag >> 20) & 7u));
}

// Pack 4 f32 -> 4 fp8 bytes (HW packed converter when available).
__device__ __forceinline__ unsigned pack_fp8x4(float y0, float y1, float y2, float y3) {
#ifdef HAS_PK_FP8
    int q = 0;
    q = __builtin_amdgcn_cvt_pk_fp8_f32(y0, y1, q, false);
    q = __builtin_amdgcn_cvt_pk_fp8_f32(y2, y3, q, true);
    return (unsigned)q;
#else
    return (unsigned)enc_fp8(y0) | ((unsigned)enc_fp8(y1) << 8) |
           ((unsigned)enc_fp8(y2) << 16) | ((unsigned)enc_fp8(y3) << 24);
#endif
}

// fp8 e4m3fn byte SEL of v -> f32 (scalar path).
template <int SEL>
__device__ __forceinline__ float dec_fp8(unsigned v) {
#ifdef HAS_CVT_FP8
    return __builtin_amdgcn_cvt_f32_fp8(v, SEL);
#else
    unsigned b = (v >> (8 * SEL)) & 0xFFu;
    unsigned e = (b >> 3) & 15u, m = b & 7u;
    float f = e ? __uint_as_float(((e + 120u) << 23) | (m << 20))
                : (float)m * 0.001953125f;
    return (b & 128u) ? -f : f;
#endif
}

// Decode all 4 fp8 bytes of v (packed HW cvt: 2 instructions).
__device__ __forceinline__ void dec4_fp8(unsigned v, float& a0, float& a1,
                                         float& a2, float& a3) {
#ifdef HAS_PK_F32_FP8
    f32x2 lo = __builtin_amdgcn_cvt_pk_f32_fp8((int)v, false);
    f32x2 hi = __builtin_amdgcn_cvt_pk_f32_fp8((int)v, true);
    a0 = lo.x; a1 = lo.y; a2 = hi.x; a3 = hi.y;
#else
    a0 = dec_fp8<0>(v); a1 = dec_fp8<1>(v);
    a2 = dec_fp8<2>(v); a3 = dec_fp8<3>(v);
#endif
}

// Seed bucket cursors and zero G.
__global__ void init_kernel(unsigned* __restrict__ gcur1,
                            unsigned* __restrict__ gcur2,
                            float* __restrict__ G) {
    int i = blockIdx.x * 256 + threadIdx.x;
    if (i < NB) {
        gcur1[i] = (unsigned)i * CAP;
        gcur2[i] = (unsigned)i * CAP;
    }
    if (i < KDIM * KDIM) G[i] = 0.0f;
}

// Fused histogram + scan + LDS-staged scatter with GLOBAL atomic range
// reservation. SINGLE idx read: chunk register-staged in 7 unrolled slots.
// Grid 2*A0B: which selects S1/S2.
__global__ __launch_bounds__(A0T) void sort_kernel(const unsigned* __restrict__ idx,
                                                   unsigned* __restrict__ gcur1,
                                                   unsigned* __restrict__ gcur2,
                                                   unsigned* __restrict__ S1,
                                                   unsigned* __restrict__ S2) {
    __shared__ unsigned stage[CHUNK];
    __shared__ unsigned lhist[NB], lcur[NB], gbase[NB];
    __shared__ unsigned wsum[16], fred[16];
    int which = blockIdx.x >> 8, chunk = blockIdx.x & (A0B - 1);
    int t = threadIdx.x, wave = t >> 6, lane = t & 63;

    unsigned hv = idx[2 * t + 1];
#pragma unroll
    for (int off = 32; off; off >>= 1) hv |= __shfl_xor(hv, off);
    if (lane == 0) fred[wave] = hv;
    for (int j = t; j < NB; j += A0T) lhist[j] = 0u;
    __syncthreads();
    unsigned o = 0;
#pragma unroll
    for (int k = 0; k < 16; ++k) o |= fred[k];
    bool i64 = (o == 0u);

    // single global read: stage the chunk's (node,edge) pairs in registers
    int base = chunk * CHUNK;
    unsigned nd[7], ed[7];
#pragma unroll
    for (int k = 0; k < 7; ++k) {
        bool ok = (k < 6) || (t < CHUNK - 6 * A0T);
        int i = base + k * A0T + t;
        nd[k] = ok ? (unsigned)load_node(idx, i, i64) : 0u;
        ed[k] = ok ? (unsigned)load_edge(idx, i, i64) : 0u;
    }

    // histogram from registers
#pragma unroll
    for (int k = 0; k < 7; ++k) {
        bool ok = (k < 6) || (t < CHUNK - 6 * A0T);
        if (ok) atomicAdd(&lhist[(which ? nd[k] : ed[k]) >> BSH], 1u);
    }
    __syncthreads();

    unsigned v = (t < NB) ? lhist[t] : 0u;
    unsigned x = v;
#pragma unroll
    for (int off = 1; off < 64; off <<= 1) {
        unsigned y = __shfl_up(x, off);
        if (lane >= off) x += y;
    }
    if (lane == 63) wsum[wave] = x;
    __syncthreads();
    if (t < 16) {
        unsigned a = wsum[t], y = a;
#pragma unroll
        for (int off = 1; off < 16; off <<= 1) {
            unsigned z = __shfl_up(y, off);
            if (t >= off) y += z;
        }
        wsum[t] = y - a;
    }
    __syncthreads();
    if (t < NB) lcur[t] = wsum[wave] + x - v;
    __syncthreads();

    // scatter from registers into LDS stage
#pragma unroll
    for (int k = 0; k < 7; ++k) {
        bool ok = (k < 6) || (t < CHUNK - 6 * A0T);
        if (ok) {
            unsigned key, val;
            if (which == 0) {
                key = ed[k] >> BSH;
                val = nd[k] | ((ed[k] & BMASK) << 17);
            } else {
                key = nd[k] >> BSH;
                val = ed[k] | ((nd[k] & BMASK) << 17);
            }
            unsigned p = atomicAdd(&lcur[key], 1u);
            stage[p] = val;
        }
    }
    __syncthreads();

    unsigned* gcur = which ? gcur2 : gcur1;
    if (t < NB) {
        unsigned c = lhist[t];
        gbase[t] = c ? atomicAdd(&gcur[t], c) : 0u;
    }
    __syncthreads();

    unsigned* S = which ? S2 : S1;
    int li = lane & 7;
    for (int bb = wave * 8 + (lane >> 3); bb < NB; bb += 128) {
        unsigned c = lhist[bb];
        unsigned st = lcur[bb] - c;
        unsigned g = gbase[bb];
        for (unsigned m = li; m < c; m += 8) S[g + m] = stage[st + m];
    }
}

// Fused Dv + Yq + term1: block b accumulates Dv for its 128 nodes in LDS,
// then normalizes/encodes those 128 Z-rows to fp8 and reduces term1.
__global__ __launch_bounds__(256) void dvyq_kernel(const unsigned* __restrict__ S2,
                                                   const unsigned* __restrict__ gcur2,
                                                   const float* __restrict__ w,
                                                   const float* __restrict__ Z,
                                                   unsigned* __restrict__ Yq32,
                                                   float* __restrict__ ZN) {
    __shared__ float accd[128];
    __shared__ float red[256];
    int t = threadIdx.x, b = blockIdx.x;
    if (t < 128) accd[t] = 0.0f;
    __syncthreads();
    unsigned cnt = gcur2[b] - (unsigned)b * CAP;
    const unsigned* src = S2 + (size_t)b * CAP;
    for (unsigned i = t; i < cnt; i += 256) {
        unsigned e = src[i];
        atomicAdd(&accd[e >> 17], w[e & 0x1FFFFu]);
    }
    __syncthreads();
    int base = b * 128;
    float zn = 0.0f;
    for (int j = t; j < 128 * 16; j += 256) {
        int row = j >> 4, q = j & 15;
        int node = base + row;
        if (node < NNODES) {
            float4 v = ((const float4*)Z)[node * 16 + q];
            float d = accd[row];
            bool good = d > 0.0f;
            float r = good ? rsqrtf(d) : 1.0f;
            zn += good ? (v.x * v.x + v.y * v.y + v.z * v.z + v.w * v.w) : 0.0f;
            Yq32[node * 16 + q] = pack_fp8x4(v.x * r, v.y * r, v.z * r, v.w * r);
        }
    }
    red[t] = zn;
    __syncthreads();
    for (int s = 128; s > 0; s >>= 1) {
        if (t < s) red[t] += red[t + s];
        __syncthreads();
    }
    if (t == 0) ZN[b] = red[0];
}

// Fused bedge + gmat: blocks [0,NB) do per-bucket edge loss (gather-latency
// bound); blocks [NB, NB+GMB) do G += Y^T Y (VALU bound). Co-resident blocks
// let the CU scheduler fill gather stalls with gmat math.
__global__ __launch_bounds__(512) void bg_kernel(const unsigned* __restrict__ Yq32,
                                                 const float* __restrict__ w,
                                                 const unsigned* __restrict__ S1,
                                                 const unsigned* __restrict__ gcur1,
                                                 float* __restrict__ part,
                                                 float* __restrict__ G) {
    __shared__ unsigned lhist[128], loffs[128], lcur[128];
    __shared__ unsigned snode[CAP];
    __shared__ float wred[8];
    __shared__ float ys[64][KDIM];
    int t = threadIdx.x, b = blockIdx.x;

    if (b >= NB) {
        // ---------------- gmat part (512 threads) ----------------
        int gb = b - NB;
        float acc[8];
#pragma unroll
        for (int i = 0; i < 8; ++i) acc[i] = 0.0f;
        int c = t & 63;
        int r0 = ((t >> 6) & 7) * 8;
        for (int base = gb * 64; base < NNODES; base += GMB * 64) {
            int rows = min(64, NNODES - base);
            __syncthreads();
            for (int j = t; j < rows * 16; j += 512) {
                unsigned v = Yq32[base * 16 + j];
                int row = j >> 4, q4 = (j & 15) * 4;
                float x0, x1, x2, x3;
                dec4_fp8(v, x0, x1, x2, x3);
                ys[row][q4 + 0] = x0;
                ys[row][q4 + 1] = x1;
                ys[row][q4 + 2] = x2;
                ys[row][q4 + 3] = x3;
            }
            __syncthreads();
#pragma unroll 4
            for (int i = 0; i < rows; ++i) {
                float yc = ys[i][c];
#pragma unroll
                for (int rr = 0; rr < 8; ++rr) acc[rr] += ys[i][r0 + rr] * yc;
            }
        }
#pragma unroll
        for (int rr = 0; rr < 8; ++rr) atomicAdd(&G[(r0 + rr) * KDIM + c], acc[rr]);
        return;
    }

    // ---------------- bedge part (R12-proven structure) ----------------
    if (t < 128) lhist[t] = 0u;
    __syncthreads();
    unsigned cnt = gcur1[b] - (unsigned)b * CAP;
    const unsigned* src = S1 + (size_t)b * CAP;
    for (unsigned i = t; i < cnt; i += 512)
        atomicAdd(&lhist[src[i] >> 17], 1u);
    __syncthreads();
    if (t < 64) {
        unsigned a = lhist[2 * t], bb = lhist[2 * t + 1];
        unsigned sp = a + bb, x = sp;
#pragma unroll
        for (int off = 1; off < 64; off <<= 1) {
            unsigned y = __shfl_up(x, off);
            if (t >= off) x += y;
        }
        unsigned ex = x - sp;
        loffs[2 * t] = ex;          lcur[2 * t] = ex;
        loffs[2 * t + 1] = ex + a;  lcur[2 * t + 1] = ex + a;
    }
    __syncthreads();
    for (unsigned i = t; i < cnt; i += 512) {
        unsigned e = src[i];
        unsigned pos = atomicAdd(&lcur[e >> 17], 1u);
        snode[pos] = e & 0x1FFFFu;
    }
    __syncthreads();
    int wv = t >> 6, lane = t & 63, ms = lane >> 4, kq = lane & 15;
    float acc = 0.0f;
    for (int el = wv; el < 64; el += 8) {
        int eA = el, eB = el + 64;
        unsigned nA = lhist[eA], nB = lhist[eB];
        if (nA == 0 && nB == 0) continue;
        unsigned begA = loffs[eA], begB = loffs[eB];
        float a0 = 0, a1 = 0, a2 = 0, a3 = 0;
        float c0 = 0, c1 = 0, c2 = 0, c3 = 0;
        unsigned mmax = nA > nB ? nA : nB;
        for (unsigned m = 0; m < mmax; m += 16) {
            unsigned mA0 = m + (unsigned)ms, mA1 = mA0 + 4, mA2 = mA0 + 8, mA3 = mA0 + 12;
            bool oA0 = mA0 < nA, oA1 = mA1 < nA, oA2 = mA2 < nA, oA3 = mA3 < nA;
            bool oB0 = mA0 < nB, oB1 = mA1 < nB, oB2 = mA2 < nB, oB3 = mA3 < nB;
            unsigned nA0 = snode[oA0 ? begA + mA0 : 0];
            unsigned nA1 = snode[oA1 ? begA + mA1 : 0];
            unsigned nA2 = snode[oA2 ? begA + mA2 : 0];
            unsigned nA3 = snode[oA3 ? begA + mA3 : 0];
            unsigned nB0 = snode[oB0 ? begB + mA0 : 0];
            unsigned nB1 = snode[oB1 ? begB + mA1 : 0];
            unsigned nB2 = snode[oB2 ? begB + mA2 : 0];
            unsigned nB3 = snode[oB3 ? begB + mA3 : 0];
            unsigned vA0 = Yq32[nA0 * 16u + (unsigned)kq];
            unsigned vA1 = Yq32[nA1 * 16u + (unsigned)kq];
            unsigned vA2 = Yq32[nA2 * 16u + (unsigned)kq];
            unsigned vA3 = Yq32[nA3 * 16u + (unsigned)kq];
            unsigned vB0 = Yq32[nB0 * 16u + (unsigned)kq];
            unsigned vB1 = Yq32[nB1 * 16u + (unsigned)kq];
            unsigned vB2 = Yq32[nB2 * 16u + (unsigned)kq];
            unsigned vB3 = Yq32[nB3 * 16u + (unsigned)kq];
            float x0, x1, x2, x3;
            dec4_fp8(vA0, x0, x1, x2, x3);
            if (oA0) { a0 += x0; a1 += x1; a2 += x2; a3 += x3; }
            dec4_fp8(vA1, x0, x1, x2, x3);
            if (oA1) { a0 += x0; a1 += x1; a2 += x2; a3 += x3; }
            dec4_fp8(vA2, x0, x1, x2, x3);
            if (oA2) { a0 += x0; a1 += x1; a2 += x2; a3 += x3; }
            dec4_fp8(vA3, x0, x1, x2, x3);
            if (oA3) { a0 += x0; a1 += x1; a2 += x2; a3 += x3; }
            dec4_fp8(vB0, x0, x1, x2, x3);
            if (oB0) { c0 += x0; c1 += x1; c2 += x2; c3 += x3; }
            dec4_fp8(vB1, x0, x1, x2, x3);
            if (oB1) { c0 += x0; c1 += x1; c2 += x2; c3 += x3; }
            dec4_fp8(vB2, x0, x1, x2, x3);
            if (oB2) { c0 += x0; c1 += x1; c2 += x2; c3 += x3; }
            dec4_fp8(vB3, x0, x1, x2, x3);
            if (oB3) { c0 += x0; c1 += x1; c2 += x2; c3 += x3; }
        }
        a0 += __shfl_xor(a0, 16); a0 += __shfl_xor(a0, 32);
        a1 += __shfl_xor(a1, 16); a1 += __shfl_xor(a1, 32);
        a2 += __shfl_xor(a2, 16); a2 += __shfl_xor(a2, 32);
        a3 += __shfl_xor(a3, 16); a3 += __shfl_xor(a3, 32);
        c0 += __shfl_xor(c0, 16); c0 += __shfl_xor(c0, 32);
        c1 += __shfl_xor(c1, 16); c1 += __shfl_xor(c1, 32);
        c2 += __shfl_xor(c2, 16); c2 += __shfl_xor(c2, 32);
        c3 += __shfl_xor(c3, 16); c3 += __shfl_xor(c3, 32);
        float aa = a0 * a0 + a1 * a1 + a2 * a2 + a3 * a3;
        float cc = c0 * c0 + c1 * c1 + c2 * c2 + c3 * c3;
        aa += __shfl_xor(aa, 1); aa += __shfl_xor(aa, 2);
        aa += __shfl_xor(aa, 4); aa += __shfl_xor(aa, 8);
        cc += __shfl_xor(cc, 1); cc += __shfl_xor(cc, 2);
        cc += __shfl_xor(cc, 4); cc += __shfl_xor(cc, 8);
        if (lane == 0) {
            if (nA) acc += (w[b * 128 + eA] / (float)nA) * aa;
            if (nB) acc += (w[b * 128 + eB] / (float)nB) * cc;
        }
    }
    if (lane == 0) wred[wv] = acc;
    __syncthreads();
    if (t == 0) {
        float s = 0.0f;
        for (int i = 0; i < 8; ++i) s += wred[i];
        part[b] = s;
    }
}

// Final: out = sum(ZN) - sum(part) + LAMBDA * ||G - I||_F
__global__ void final_kernel(const float* __restrict__ G,
                             const float* __restrict__ ZN,
                             const float* __restrict__ part,
                             float* __restrict__ out) {
    __shared__ float r1[256], r2[256];
    int t = threadIdx.x;
    float zn = 0.0f, pe = 0.0f, gg = 0.0f;
    for (int i = t; i < NB; i += 256) { zn += ZN[i]; pe += part[i]; }
    for (int i = t; i < KDIM * KDIM; i += 256) {
        int r = i >> 6, c = i & 63;
        float g = G[i] - ((r == c) ? 1.0f : 0.0f);
        gg += g * g;
    }
    r1[t] = zn - pe; r2[t] = gg;
    __syncthreads();
    for (int s = 128; s > 0; s >>= 1) {
        if (t < s) { r1[t] += r1[t + s]; r2[t] += r2[t + s]; }
        __syncthreads();
    }
    if (t == 0) out[0] = r1[0] + LAMBDA * sqrtf(r2[0]);
}

extern "C" void kernel_launch(void* const* d_in, const int* in_sizes, int n_in,
                              void* d_out, int out_size, void* d_ws, size_t ws_size,
                              hipStream_t stream) {
    const float* Z = (const float*)d_in[0];
    const unsigned* idx = (const unsigned*)d_in[1];
    const float* w = (const float*)d_in[3];
    float* out = (float*)d_out;
    char* ws = (char*)d_ws;

    float* G        = (float*)(ws + OFF_G);
    float* part     = (float*)(ws + OFF_PART);
    float* ZN       = (float*)(ws + OFF_ZN);
    unsigned* gcur1 = (unsigned*)(ws + OFF_GC1);
    unsigned* gcur2 = (unsigned*)(ws + OFF_GC2);
    unsigned* S1    = (unsigned*)(ws + OFF_S1);
    unsigned* S2    = (unsigned*)(ws + OFF_S2);
    unsigned* Yq32  = (unsigned*)(ws + OFF_YQ);

    init_kernel<<<16, 256, 0, stream>>>(gcur1, gcur2, G);
    sort_kernel<<<2 * A0B, A0T, 0, stream>>>(idx, gcur1, gcur2, S1, S2);
    dvyq_kernel<<<NB, 256, 0, stream>>>(S2, gcur2, w, Z, Yq32, ZN);
    bg_kernel<<<NB + GMB, 512, 0, stream>>>(Yq32, w, S1, gcur1, part, G);
    final_kernel<<<1, 256, 0, stream>>>(G, ZN, part, out);
}